// Round 11
// baseline (2167.936 us; speedup 1.0000x reference)
//
#include <hip/hip_runtime.h>

#define HH 1024
#define FOURH 4096
#define BB 256
#define TT 192
#define WARM 64
#define NSTEP 256        // 128 warm + 127 decode + 1 final-output-only iteration
#define UPB 16           // units per block
#define LDS_BYTES 152704

typedef _Float16 f16;
typedef _Float16 f16x8 __attribute__((ext_vector_type(8)));
typedef float    f32x4 __attribute__((ext_vector_type(4)));
typedef int      i32x4 __attribute__((ext_vector_type(4)));

// workspace layout (bytes):
//   [0, 4 MiB)       : hx 8-slot ring, f16 [8 slot][4 mg][64 kc][64 row][16 u]
//   [4 MiB, +4 KiB)  : per-mg step flags: u32 flg[4 mg][256] (only [0..63] used per mg)
//   [+4 KiB, +1 MiB) : pred partials, 8-slot ring: f32 [8 slot][4 mg][64 nblk][64 row][2]
#define HX_SLOT 524288
#define FLG_OFF 4194304
#define PP_OFF  (FLG_OFF + 4096)

__global__ void init_ws(unsigned int* ws) {
  int i = blockIdx.x * 256 + threadIdx.x;
  if (i < 131072) ws[i] = 0u;                               // hx slot 0 = initial h = 0
  else if (i < 132096) ws[FLG_OFF / 4 + (i - 131072)] = 0u; // flags
}

__device__ __forceinline__ float fsig(float x) { return 1.0f / (1.0f + __expf(-x)); }
__device__ __forceinline__ float ftanh(float x) {
  float ax = fabsf(x);
  float e  = __expf(-2.0f * ax);
  float t  = (1.0f - e) / (1.0f + e);
  return x < 0.0f ? -t : t;
}

// ---- agent-scope (device-coherent, cache-bypassing) wide VMEM via asm ----
__device__ __forceinline__ i32x4 ald16(const void* p) {
  i32x4 v;
  asm volatile("global_load_dwordx4 %0, %1, off sc0 sc1" : "=v"(v) : "v"(p) : "memory");
  return v;
}
__device__ __forceinline__ void ast16(void* p, i32x4 v) {
  asm volatile("global_store_dwordx4 %0, %1, off sc0 sc1" :: "v"(p), "v"(v) : "memory");
}
// ---- plain cached 16B load: coherence via 8-slot rings + buffer_inv every 8 steps.
// Safe because ALL kernel global writes are write-through (sc0 sc1): L3 is always
// authoritative, L2 re-population is always fresh, and each ring slot sees exactly one
// self-inv between consecutive reads (slot X read only at one step-residue mod 8).
__device__ __forceinline__ i32x4 cld16(const void* p) {
  i32x4 v;
  asm volatile("global_load_dwordx4 %0, %1, off" : "=v"(v) : "v"(p) : "memory");
  return v;
}
#define VWAIT(n) asm volatile("s_waitcnt vmcnt(" #n ")" ::: "memory")
__device__ __forceinline__ void vfence() { asm volatile("s_waitcnt vmcnt(0)" ::: "memory"); }
__device__ __forceinline__ i32x4 pass(i32x4 v) { asm volatile("" : "+v"(v)); return v; }

__device__ __forceinline__ void cst32(void* p, unsigned int v) {
  __hip_atomic_store((unsigned int*)p, v, __ATOMIC_RELAXED, __HIP_MEMORY_SCOPE_AGENT);
}
__device__ __forceinline__ void cstf(float* p, float v) {
  __hip_atomic_store(p, v, __ATOMIC_RELAXED, __HIP_MEMORY_SCOPE_AGENT);
}
__device__ __forceinline__ int imin4(int a, int b, int c, int d) {
  int x = a < b ? a : b;
  int y = c < d ? c : d;
  return x < y ? x : y;
}

__launch_bounds__(512, 1)
__global__ void lstm_persist(const float* __restrict__ inp,
                             const float* __restrict__ Wx,
                             const float* __restrict__ Wh,
                             const float* __restrict__ bias,
                             const float* __restrict__ Wd,
                             const float* __restrict__ bdp,
                             float* __restrict__ out,
                             unsigned char* __restrict__ ws)
{
  extern __shared__ char smem[];
  f16*   Wl     = (f16*)smem;                    // 131072 B, B-frag swizzled
  float* z_lds  = (float*)(smem + 131072);       // 64 x 68 fp32 = 17408 B
  float* x_sh   = z_lds + 64 * 68;               // 64 x 2
  float* mask_sh= x_sh + 128;                    // 64
  float* wx0_sh = mask_sh + 64;                  // 64
  float* wx1_sh = wx0_sh + 64;                   // 64
  float* b_sh   = wx1_sh + 64;                   // 64
  float* wd_sh  = b_sh + 64;                     // 32
  f16*   hsh    = (f16*)(wd_sh + 32);            // 64 row x 16 u f16 = 2048 B
  float* pps    = (float*)(hsh + 1024);          // 64 row x 2 f32 = 512 B

  const int tid  = threadIdx.x;
  const int bx   = blockIdx.x;
  const int mg   = bx >> 6;         // 4 batch groups of 64 rows (independent LSTMs)
  const int nblk = bx & 63;         // 64 unit-groups of 16 units
  const int ublk = nblk * UPB;

  // ---------------- prologue: stage Wh slice into LDS in B-fragment order ----------------
  {
    const int wrow = tid >> 6;           // 0..7
    const int l    = tid & 63;
    const int gate = l >> 4;
    const int u    = l & 15;
    const int gcol = gate * HH + ublk + u;
    for (int rb = 0; rb < 128; rb += 8) {
      float v[8];
#pragma unroll
      for (int ii = 0; ii < 8; ++ii) {
        int r = (rb + ii) * 8 + wrow;
        v[ii] = Wh[r * FOURH + gcol];
      }
#pragma unroll
      for (int ii = 0; ii < 8; ++ii) {
        int r = (rb + ii) * 8 + wrow;
        int kk = r >> 5, sub = r & 31, q = sub >> 3, j = sub & 7;
        Wl[((kk * 4 + gate) * 64 + (q * 16 + u)) * 8 + j] = (f16)v[ii];
      }
    }
    if (tid < 64) {
      int g2 = tid >> 4, u2 = tid & 15;
      int gc = g2 * HH + ublk + u2;
      wx0_sh[tid] = Wx[gc];
      wx1_sh[tid] = Wx[FOURH + gc];
      b_sh[tid]   = bias[gc];
    }
    if (tid < UPB) {
      wd_sh[tid * 2 + 0] = Wd[(ublk + tid) * 2 + 0];
      wd_sh[tid * 2 + 1] = Wd[(ublk + tid) * 2 + 1];
    }
  }
  __syncthreads();

  // phase-C ownership: unit u_ep, rows r0 and r0+32
  const int u_ep = tid & 15;
  const int r0   = tid >> 4;           // 0..31
  float c_reg[2] = {0.f, 0.f};
  float h_reg[2] = {0.f, 0.f};

  // wave roles (2-stage merge partition): wave (kd, mh) owns rows 16*mh..+16 and
  // k-half [512*kd, 512*kd+512). Same per-wave load volume (16x16B) and MFMA count
  // (64) as the 4-quarter partition, but z-merge needs only 2 ordered stages.
  const int wid  = tid >> 6;           // 0..7
  const int kd   = wid & 1;            // k-half: 512 k each
  const int mh   = wid >> 1;           // row-sixteenth: 16 rows each (0..3)
  const int lane = tid & 63;
  const int lm   = lane & 15;
  const int lq   = lane >> 4;

  const float bd0 = bdp[0], bd1 = bdp[1];

  for (int s = 0; s < NSTEP; ++s) {
    const bool decode = (s >= 128);

    // ---- coherence epoch: every 8 steps drop (clean) L1 + this XCD's L2 lines.
    // Write-through global stores mean no dirty data can be lost. (Also a rejoin
    // point for the per-wave poll below.)
    if ((s & 7) == 0) {
      if (wid == 0) {
        asm volatile("buffer_inv sc1" ::: "memory");
        vfence();
      }
      __syncthreads();
    }

    // ---------------- phase A-issue: pred-partial loads (decode, all 512 threads) -------
    // pp slot written at step s-1 is (s-1)&7 == (s+7)&7; read via CACHED loads (L2-shared
    // across the 32 blocks/XCD after first touch; same ring-inv safety as hx).
    i32x4 ppv[4];
    if (decode) {
      const char* pb = (const char*)ws + PP_OFF
                     + (size_t)((((s + 7) & 7) * 4 + mg) * 64) * 512 + r0 * 16;
#pragma unroll
      for (int i = 0; i < 4; ++i) ppv[i] = cld16(pb + (u_ep + 16 * i) * 512);
    } else {
      if (tid < 64) {
        int row = tid;
        const float* ip = inp + ((mg * 64 + row) * TT + (WARM + s)) * 2;
        float i0 = ip[0], i1 = ip[1];
        bool m = (i0 != -1.0f) || (i1 != -1.0f);
        x_sh[row * 2 + 0] = m ? i0 : 0.0f;
        x_sh[row * 2 + 1] = m ? i1 : 0.0f;
        mask_sh[row]      = m ? 1.0f : 0.0f;
      }
    }

    // ---------------- A-fragments: cached 16B loads from ring slot s&7 ----------------
    // wave (kd,mh) = rows 16*mh..+16, k in [512*kd, 512*kd+512). One 16B load per
    // 32-k MFMA step: kc = kd*32 + 2*ksi + (lq>>1), row = 16*mh + lm, half = lq&1.
    // (MFMA A layout: lane holds row lm, k-subchunk 8*lq of the 32-k step.)
    i32x4 q[16];
    {
      const char* ab = (const char*)ws + (s & 7) * HX_SLOT + mg * 131072
                     + (kd * 32 + (lq >> 1)) * 2048 + (16 * mh + lm) * 32 + (lq & 1) * 16;
#pragma unroll
      for (int ksi = 0; ksi < 16; ++ksi)
        q[ksi] = cld16(ab + ksi * 4096);
    }

    // ---------------- phase A-complete: pred reduce (hides under A fill) ----------------
    if (decode) {
      VWAIT(16);                     // 4 oldest (pp) done; 16 A-loads still in flight
      f32x4 v = __builtin_bit_cast(f32x4, pass(ppv[0]));
      v += __builtin_bit_cast(f32x4, pass(ppv[1]));
      v += __builtin_bit_cast(f32x4, pass(ppv[2]));
      v += __builtin_bit_cast(f32x4, pass(ppv[3]));
#pragma unroll
      for (int m2 = 1; m2 < 16; m2 <<= 1) {
        v.x += __shfl_xor(v.x, m2, 64);
        v.y += __shfl_xor(v.y, m2, 64);
        v.z += __shfl_xor(v.z, m2, 64);
        v.w += __shfl_xor(v.w, m2, 64);
      }
      if (u_ep == 0) {               // rows 2*r0, 2*r0+1, both outputs
        v.x += bd0; v.y += bd1; v.z += bd0; v.w += bd1;
        *(f32x4*)(x_sh + r0 * 4) = v;
        if (nblk == 0) {
          float* o = out + (size_t)((mg * 64 + 2 * r0) * 128 + (s - 128)) * 2;
          cstf(o, v.x); cstf(o + 1, v.y); cstf(o + 256, v.z); cstf(o + 257, v.w);
        }
      }
      if (s == NSTEP - 1) break;     // uniform across the whole grid
    }

    // ---------------- phase B: MFMA, graded vmcnt (compute ksi0-7 while 8-15 fill) -----
    f32x4 acc[4];
#pragma unroll
    for (int n = 0; n < 4; ++n) acc[n] = f32x4{0.f, 0.f, 0.f, 0.f};

    VWAIT(8);                        // q[0..7] resident
#pragma unroll
    for (int ksi = 0; ksi < 8; ++ksi) {
      const f16* bb = Wl + (kd * 16 + ksi) * 2048 + lane * 8;
      f16x8 b0 = *(const f16x8*)(bb);
      f16x8 b1 = *(const f16x8*)(bb + 512);
      f16x8 b2 = *(const f16x8*)(bb + 1024);
      f16x8 b3 = *(const f16x8*)(bb + 1536);
      f16x8 a  = __builtin_bit_cast(f16x8, pass(q[ksi]));
      acc[0] = __builtin_amdgcn_mfma_f32_16x16x32_f16(a, b0, acc[0], 0, 0, 0);
      acc[1] = __builtin_amdgcn_mfma_f32_16x16x32_f16(a, b1, acc[1], 0, 0, 0);
      acc[2] = __builtin_amdgcn_mfma_f32_16x16x32_f16(a, b2, acc[2], 0, 0, 0);
      acc[3] = __builtin_amdgcn_mfma_f32_16x16x32_f16(a, b3, acc[3], 0, 0, 0);
    }
    VWAIT(0);                        // q[8..15] resident
#pragma unroll
    for (int ksi = 8; ksi < 16; ++ksi) {
      const f16* bb = Wl + (kd * 16 + ksi) * 2048 + lane * 8;
      f16x8 b0 = *(const f16x8*)(bb);
      f16x8 b1 = *(const f16x8*)(bb + 512);
      f16x8 b2 = *(const f16x8*)(bb + 1024);
      f16x8 b3 = *(const f16x8*)(bb + 1536);
      f16x8 a  = __builtin_bit_cast(f16x8, pass(q[ksi]));
      acc[0] = __builtin_amdgcn_mfma_f32_16x16x32_f16(a, b0, acc[0], 0, 0, 0);
      acc[1] = __builtin_amdgcn_mfma_f32_16x16x32_f16(a, b1, acc[1], 0, 0, 0);
      acc[2] = __builtin_amdgcn_mfma_f32_16x16x32_f16(a, b2, acc[2], 0, 0, 0);
      acc[3] = __builtin_amdgcn_mfma_f32_16x16x32_f16(a, b3, acc[3], 0, 0, 0);
    }

    // ---------------- z merge: 2 sequential k-half stages (race-free by rows) ----------
    // C/D layout: row = 16*mh + 4*lq + r, col = 16*n + lm
#pragma unroll
    for (int stage = 0; stage < 2; ++stage) {
      if (kd == stage) {
        const int rb = 16 * mh + 4 * lq;
#pragma unroll
        for (int n = 0; n < 4; ++n) {
#pragma unroll
          for (int r = 0; r < 4; ++r) {
            float* zp = &z_lds[(rb + r) * 68 + 16 * n + lm];
            if (stage == 0) *zp = acc[n][r];
            else            *zp += acc[n][r];
          }
        }
      }
      __syncthreads();
    }

    // ---------------- phase C: gates + state update ----------------
    const bool wr_pred = (s >= 127);
#pragma unroll
    for (int q4 = 0; q4 < 2; ++q4) {
      int row = r0 + 32 * q4;
      float x0 = x_sh[row * 2], x1 = x_sh[row * 2 + 1];
      float* zr = z_lds + row * 68;
      float zi = zr[     u_ep] + x0 * wx0_sh[     u_ep] + x1 * wx1_sh[     u_ep] + b_sh[     u_ep];
      float zf = zr[16 + u_ep] + x0 * wx0_sh[16 + u_ep] + x1 * wx1_sh[16 + u_ep] + b_sh[16 + u_ep];
      float zg = zr[32 + u_ep] + x0 * wx0_sh[32 + u_ep] + x1 * wx1_sh[32 + u_ep] + b_sh[32 + u_ep];
      float zo = zr[48 + u_ep] + x0 * wx0_sh[48 + u_ep] + x1 * wx1_sh[48 + u_ep] + b_sh[48 + u_ep];
      float ig = fsig(zi), fg = fsig(zf), gg = ftanh(zg), og = fsig(zo);
      float cn = fg * c_reg[q4] + ig * gg;
      float hn = og * ftanh(cn);
      if (!decode) {
        bool m = mask_sh[row] > 0.5f;
        cn = m ? cn : c_reg[q4];
        hn = m ? hn : h_reg[q4];
      }
      c_reg[q4] = cn; h_reg[q4] = hn;

      hsh[row * 16 + u_ep] = (f16)hn;

      if (wr_pred) {
        float p0 = hn * wd_sh[u_ep * 2 + 0];
        float p1 = hn * wd_sh[u_ep * 2 + 1];
#pragma unroll
        for (int m2 = 1; m2 < 16; m2 <<= 1) {
          p0 += __shfl_xor(p0, m2, 64);
          p1 += __shfl_xor(p1, m2, 64);
        }
        if (u_ep == 0) { pps[row * 2] = p0; pps[row * 2 + 1] = p1; }
      }
    }

    // ---------------- per-wave self-bounce: wave w bounces ONLY rows its own lanes
    // ---------------- wrote to hsh/pps (rows 4w..4w+3, 4w+32..35) -> no __syncthreads
    asm volatile("" ::: "memory");                 // keep LDS writes above the reads
    {
      if (lane < 16) {
        int idx = lane >> 1, oct = lane & 1;
        int row = (idx < 4) ? (4 * wid + idx) : (28 + 4 * wid + idx);
        f16x8 hv = *(const f16x8*)(hsh + row * 16 + oct * 8);
        char* dst = (char*)ws + ((s + 1) & 7) * HX_SLOT + mg * 131072 + nblk * 2048
                  + row * 32 + oct * 16;
        ast16(dst, __builtin_bit_cast(i32x4, hv));
      }
      if (wr_pred && lane < 4) {
        int row = (lane < 2) ? (4 * wid + 2 * lane) : (4 * wid + 32 + 2 * (lane - 2));
        f32x4 pv = *(const f32x4*)(pps + row * 2);
        char* dst = (char*)ws + PP_OFF + (size_t)(((s & 7) * 4 + mg) * 64 + nblk) * 512
                  + row * 8;
        ast16(dst, __builtin_bit_cast(i32x4, pv));
      }
      vfence();                                    // drain this wave's stores
    }
    __syncthreads();                               // bar3: ALL waves' stores drained;
                                                   // also the last phase-C LDS reads

    // ---------------- per-mg barrier: tid0 flag store + PER-WAVE poll (bar4 removed) ---
    // Flag protocol byte-identical to R8 (one cst32 per block). Each wave now polls the
    // same 4 flag lines itself (lanes replicate lane&15 -> one coalesced 4-line request
    // per iteration) and proceeds into the next step the moment it detects; the next
    // step's merge barriers (and the epoch barrier) rejoin the waves. All cross-step
    // LDS hazards are closed by bar3 above (phase-C reads complete before any wave can
    // write z/x_sh/mask of the next step).
    {
      unsigned int* fl = (unsigned int*)((char*)ws + FLG_OFF + mg * 1024);
      if (tid == 0) cst32(fl + nblk, (unsigned int)(s + 1));
      const char* fp = (const char*)fl + (lane & 15) * 16;
      const int tgt = s + 1;
      int guard = 0;
      for (;;) {
        i32x4 f = ald16(fp);
        vfence();
        f = pass(f);
        int mn = imin4(f.x, f.y, f.z, f.w);
        if (__all(mn >= tgt)) break;
        if (++guard > 200000) break;               // bail-out: never hang the bench
        __builtin_amdgcn_s_sleep(1);
      }
    }
  }
  vfence();
}

extern "C" void kernel_launch(void* const* d_in, const int* in_sizes, int n_in,
                              void* d_out, int out_size, void* d_ws, size_t ws_size,
                              hipStream_t stream) {
  const float* inp = (const float*)d_in[0];
  const float* Wx  = (const float*)d_in[1];
  const float* Wh  = (const float*)d_in[2];
  const float* b   = (const float*)d_in[3];
  const float* Wd  = (const float*)d_in[4];
  const float* bd  = (const float*)d_in[5];
  float* out = (float*)d_out;
  unsigned char* ws = (unsigned char*)d_ws;

  init_ws<<<517, 256, 0, stream>>>((unsigned int*)ws);

  hipFuncSetAttribute((const void*)lstm_persist,
                      hipFuncAttributeMaxDynamicSharedMemorySize, LDS_BYTES);
  lstm_persist<<<256, 512, LDS_BYTES, stream>>>(inp, Wx, Wh, b, Wd, bd, out, ws);
}

// Round 12
// 1967.925 us; speedup vs baseline: 1.1016x; 1.1016x over previous
//
#include <hip/hip_runtime.h>

#define HH 1024
#define FOURH 4096
#define BB 256
#define TT 192
#define WARM 64
#define NSTEP 256        // 128 warm + 127 decode + 1 final-output-only iteration
#define UPB 16           // units per block
#define LDS_BYTES 152704

typedef _Float16 f16;
typedef _Float16 f16x8 __attribute__((ext_vector_type(8)));
typedef float    f32x4 __attribute__((ext_vector_type(4)));
typedef int      i32x4 __attribute__((ext_vector_type(4)));

// workspace layout (bytes):
//   [0, 4 MiB)       : hx 8-slot ring, f16 [8 slot][4 mg][64 kc][64 row][16 u]
//   [4 MiB, +4 KiB)  : per-mg step flags: u32 flg[4 mg][256] (only [0..63] used per mg)
//   [+4 KiB, +1 MiB) : pred partials, 8-slot ring: f32 [8 slot][4 mg][64 nblk][64 row][2]
#define HX_SLOT 524288
#define FLG_OFF 4194304
#define PP_OFF  (FLG_OFF + 4096)

__global__ void init_ws(unsigned int* ws) {
  int i = blockIdx.x * 256 + threadIdx.x;
  if (i < 131072) ws[i] = 0u;                               // hx slot 0 = initial h = 0
  else if (i < 132096) ws[FLG_OFF / 4 + (i - 131072)] = 0u; // flags
}

__device__ __forceinline__ float fsig(float x) { return 1.0f / (1.0f + __expf(-x)); }
__device__ __forceinline__ float ftanh(float x) {
  float ax = fabsf(x);
  float e  = __expf(-2.0f * ax);
  float t  = (1.0f - e) / (1.0f + e);
  return x < 0.0f ? -t : t;
}

// ---- agent-scope (device-coherent, cache-bypassing) wide VMEM via asm ----
__device__ __forceinline__ i32x4 ald16(const void* p) {
  i32x4 v;
  asm volatile("global_load_dwordx4 %0, %1, off sc0 sc1" : "=v"(v) : "v"(p) : "memory");
  return v;
}
__device__ __forceinline__ void ast16(void* p, i32x4 v) {
  asm volatile("global_store_dwordx4 %0, %1, off sc0 sc1" :: "v"(p), "v"(v) : "memory");
}
// ---- plain cached 16B load: coherence via 8-slot rings + buffer_inv every 8 steps.
// Safe because ALL kernel global writes are write-through (sc0 sc1): L3 is always
// authoritative, L2 re-population is always fresh, and each ring slot sees exactly one
// self-inv between consecutive reads (slot X read only at one step-residue mod 8).
__device__ __forceinline__ i32x4 cld16(const void* p) {
  i32x4 v;
  asm volatile("global_load_dwordx4 %0, %1, off" : "=v"(v) : "v"(p) : "memory");
  return v;
}
#define VWAIT(n) asm volatile("s_waitcnt vmcnt(" #n ")" ::: "memory")
__device__ __forceinline__ void vfence() { asm volatile("s_waitcnt vmcnt(0)" ::: "memory"); }
__device__ __forceinline__ i32x4 pass(i32x4 v) { asm volatile("" : "+v"(v)); return v; }

__device__ __forceinline__ void cst32(void* p, unsigned int v) {
  __hip_atomic_store((unsigned int*)p, v, __ATOMIC_RELAXED, __HIP_MEMORY_SCOPE_AGENT);
}
__device__ __forceinline__ void cstf(float* p, float v) {
  __hip_atomic_store(p, v, __ATOMIC_RELAXED, __HIP_MEMORY_SCOPE_AGENT);
}
__device__ __forceinline__ int imin4(int a, int b, int c, int d) {
  int x = a < b ? a : b;
  int y = c < d ? c : d;
  return x < y ? x : y;
}

__launch_bounds__(512, 1)
__global__ void lstm_persist(const float* __restrict__ inp,
                             const float* __restrict__ Wx,
                             const float* __restrict__ Wh,
                             const float* __restrict__ bias,
                             const float* __restrict__ Wd,
                             const float* __restrict__ bdp,
                             float* __restrict__ out,
                             unsigned char* __restrict__ ws)
{
  extern __shared__ char smem[];
  f16*   Wl     = (f16*)smem;                    // 131072 B, B-frag swizzled
  float* z_lds  = (float*)(smem + 131072);       // 64 x 68 fp32 = 17408 B
  float* x_sh   = z_lds + 64 * 68;               // 64 x 2
  float* mask_sh= x_sh + 128;                    // 64
  float* wx0_sh = mask_sh + 64;                  // 64
  float* wx1_sh = wx0_sh + 64;                   // 64
  float* b_sh   = wx1_sh + 64;                   // 64
  float* wd_sh  = b_sh + 64;                     // 32
  f16*   hsh    = (f16*)(wd_sh + 32);            // 64 row x 16 u f16 = 2048 B
  float* pps    = (float*)(hsh + 1024);          // 64 row x 2 f32 = 512 B

  const int tid  = threadIdx.x;
  const int bx   = blockIdx.x;
  const int mg   = bx >> 6;         // 4 batch groups of 64 rows (independent LSTMs)
  const int nblk = bx & 63;         // 64 unit-groups of 16 units
  const int ublk = nblk * UPB;

  // ---------------- prologue: stage Wh slice into LDS in B-fragment order ----------------
  {
    const int wrow = tid >> 6;           // 0..7
    const int l    = tid & 63;
    const int gate = l >> 4;
    const int u    = l & 15;
    const int gcol = gate * HH + ublk + u;
    for (int rb = 0; rb < 128; rb += 8) {
      float v[8];
#pragma unroll
      for (int ii = 0; ii < 8; ++ii) {
        int r = (rb + ii) * 8 + wrow;
        v[ii] = Wh[r * FOURH + gcol];
      }
#pragma unroll
      for (int ii = 0; ii < 8; ++ii) {
        int r = (rb + ii) * 8 + wrow;
        int kk = r >> 5, sub = r & 31, q = sub >> 3, j = sub & 7;
        Wl[((kk * 4 + gate) * 64 + (q * 16 + u)) * 8 + j] = (f16)v[ii];
      }
    }
    if (tid < 64) {
      int g2 = tid >> 4, u2 = tid & 15;
      int gc = g2 * HH + ublk + u2;
      wx0_sh[tid] = Wx[gc];
      wx1_sh[tid] = Wx[FOURH + gc];
      b_sh[tid]   = bias[gc];
    }
    if (tid < UPB) {
      wd_sh[tid * 2 + 0] = Wd[(ublk + tid) * 2 + 0];
      wd_sh[tid * 2 + 1] = Wd[(ublk + tid) * 2 + 1];
    }
  }
  __syncthreads();

  // phase-C ownership: unit u_ep, rows r0 and r0+32
  const int u_ep = tid & 15;
  const int r0   = tid >> 4;           // 0..31
  float c_reg[2] = {0.f, 0.f};
  float h_reg[2] = {0.f, 0.f};

  // wave roles (2-stage merge partition): wave (kd, mh) owns rows 16*mh..+16 and
  // k-half [512*kd, 512*kd+512). Same per-wave load volume (16x16B) and MFMA count
  // (64) as the 4-quarter partition, but z-merge needs only 2 ordered stages.
  const int wid  = tid >> 6;           // 0..7
  const int kd   = wid & 1;            // k-half: 512 k each
  const int mh   = wid >> 1;           // row-sixteenth: 16 rows each (0..3)
  const int lane = tid & 63;
  const int lm   = lane & 15;
  const int lq   = lane >> 4;

  const float bd0 = bdp[0], bd1 = bdp[1];

  for (int s = 0; s < NSTEP; ++s) {
    const bool decode = (s >= 128);

    // ---- coherence epoch: every 8 steps drop (clean) L1 + this XCD's L2 lines.
    // Write-through global stores mean no dirty data can be lost.
    if ((s & 7) == 0) {
      if (wid == 0) {
        asm volatile("buffer_inv sc1" ::: "memory");
        vfence();
      }
      __syncthreads();
    }

    // ---------------- phase A-issue: pred-partial loads (decode, all 512 threads) -------
    // pp slot written at step s-1 is (s-1)&7 == (s+7)&7; read via CACHED loads (L2-shared
    // across the 32 blocks/XCD after first touch; same ring-inv safety as hx).
    i32x4 ppv[4];
    if (decode) {
      const char* pb = (const char*)ws + PP_OFF
                     + (size_t)((((s + 7) & 7) * 4 + mg) * 64) * 512 + r0 * 16;
#pragma unroll
      for (int i = 0; i < 4; ++i) ppv[i] = cld16(pb + (u_ep + 16 * i) * 512);
    } else {
      if (tid < 64) {
        int row = tid;
        const float* ip = inp + ((mg * 64 + row) * TT + (WARM + s)) * 2;
        float i0 = ip[0], i1 = ip[1];
        bool m = (i0 != -1.0f) || (i1 != -1.0f);
        x_sh[row * 2 + 0] = m ? i0 : 0.0f;
        x_sh[row * 2 + 1] = m ? i1 : 0.0f;
        mask_sh[row]      = m ? 1.0f : 0.0f;
      }
    }

    // ---------------- A-fragments: cached 16B loads from ring slot s&7 ----------------
    // wave (kd,mh) = rows 16*mh..+16, k in [512*kd, 512*kd+512). One 16B load per
    // 32-k MFMA step: kc = kd*32 + 2*ksi + (lq>>1), row = 16*mh + lm, half = lq&1.
    // (MFMA A layout: lane holds row lm, k-subchunk 8*lq of the 32-k step.)
    i32x4 q[16];
    {
      const char* ab = (const char*)ws + (s & 7) * HX_SLOT + mg * 131072
                     + (kd * 32 + (lq >> 1)) * 2048 + (16 * mh + lm) * 32 + (lq & 1) * 16;
#pragma unroll
      for (int ksi = 0; ksi < 16; ++ksi)
        q[ksi] = cld16(ab + ksi * 4096);
    }

    // ---------------- phase A-complete: pred reduce (hides under A fill) ----------------
    if (decode) {
      VWAIT(16);                     // 4 oldest (pp) done; 16 A-loads still in flight
      f32x4 v = __builtin_bit_cast(f32x4, pass(ppv[0]));
      v += __builtin_bit_cast(f32x4, pass(ppv[1]));
      v += __builtin_bit_cast(f32x4, pass(ppv[2]));
      v += __builtin_bit_cast(f32x4, pass(ppv[3]));
#pragma unroll
      for (int m2 = 1; m2 < 16; m2 <<= 1) {
        v.x += __shfl_xor(v.x, m2, 64);
        v.y += __shfl_xor(v.y, m2, 64);
        v.z += __shfl_xor(v.z, m2, 64);
        v.w += __shfl_xor(v.w, m2, 64);
      }
      if (u_ep == 0) {               // rows 2*r0, 2*r0+1, both outputs
        v.x += bd0; v.y += bd1; v.z += bd0; v.w += bd1;
        *(f32x4*)(x_sh + r0 * 4) = v;
        if (nblk == 0) {
          float* o = out + (size_t)((mg * 64 + 2 * r0) * 128 + (s - 128)) * 2;
          cstf(o, v.x); cstf(o + 1, v.y); cstf(o + 256, v.z); cstf(o + 257, v.w);
        }
      }
      if (s == NSTEP - 1) break;     // uniform across the whole grid
    }

    // ---------------- phase B: MFMA, graded vmcnt (compute ksi0-7 while 8-15 fill) -----
    f32x4 acc[4];
#pragma unroll
    for (int n = 0; n < 4; ++n) acc[n] = f32x4{0.f, 0.f, 0.f, 0.f};

    VWAIT(8);                        // q[0..7] resident
#pragma unroll
    for (int ksi = 0; ksi < 8; ++ksi) {
      const f16* bb = Wl + (kd * 16 + ksi) * 2048 + lane * 8;
      f16x8 b0 = *(const f16x8*)(bb);
      f16x8 b1 = *(const f16x8*)(bb + 512);
      f16x8 b2 = *(const f16x8*)(bb + 1024);
      f16x8 b3 = *(const f16x8*)(bb + 1536);
      f16x8 a  = __builtin_bit_cast(f16x8, pass(q[ksi]));
      acc[0] = __builtin_amdgcn_mfma_f32_16x16x32_f16(a, b0, acc[0], 0, 0, 0);
      acc[1] = __builtin_amdgcn_mfma_f32_16x16x32_f16(a, b1, acc[1], 0, 0, 0);
      acc[2] = __builtin_amdgcn_mfma_f32_16x16x32_f16(a, b2, acc[2], 0, 0, 0);
      acc[3] = __builtin_amdgcn_mfma_f32_16x16x32_f16(a, b3, acc[3], 0, 0, 0);
    }
    VWAIT(0);                        // q[8..15] resident
#pragma unroll
    for (int ksi = 8; ksi < 16; ++ksi) {
      const f16* bb = Wl + (kd * 16 + ksi) * 2048 + lane * 8;
      f16x8 b0 = *(const f16x8*)(bb);
      f16x8 b1 = *(const f16x8*)(bb + 512);
      f16x8 b2 = *(const f16x8*)(bb + 1024);
      f16x8 b3 = *(const f16x8*)(bb + 1536);
      f16x8 a  = __builtin_bit_cast(f16x8, pass(q[ksi]));
      acc[0] = __builtin_amdgcn_mfma_f32_16x16x32_f16(a, b0, acc[0], 0, 0, 0);
      acc[1] = __builtin_amdgcn_mfma_f32_16x16x32_f16(a, b1, acc[1], 0, 0, 0);
      acc[2] = __builtin_amdgcn_mfma_f32_16x16x32_f16(a, b2, acc[2], 0, 0, 0);
      acc[3] = __builtin_amdgcn_mfma_f32_16x16x32_f16(a, b3, acc[3], 0, 0, 0);
    }

    // ---------------- z merge: 2 sequential k-half stages (race-free by rows) ----------
    // C/D layout: row = 16*mh + 4*lq + r, col = 16*n + lm
#pragma unroll
    for (int stage = 0; stage < 2; ++stage) {
      if (kd == stage) {
        const int rb = 16 * mh + 4 * lq;
#pragma unroll
        for (int n = 0; n < 4; ++n) {
#pragma unroll
          for (int r = 0; r < 4; ++r) {
            float* zp = &z_lds[(rb + r) * 68 + 16 * n + lm];
            if (stage == 0) *zp = acc[n][r];
            else            *zp += acc[n][r];
          }
        }
      }
      __syncthreads();
    }

    // ---------------- phase C: gates + state update ----------------
    const bool wr_pred = (s >= 127);
#pragma unroll
    for (int q4 = 0; q4 < 2; ++q4) {
      int row = r0 + 32 * q4;
      float x0 = x_sh[row * 2], x1 = x_sh[row * 2 + 1];
      float* zr = z_lds + row * 68;
      float zi = zr[     u_ep] + x0 * wx0_sh[     u_ep] + x1 * wx1_sh[     u_ep] + b_sh[     u_ep];
      float zf = zr[16 + u_ep] + x0 * wx0_sh[16 + u_ep] + x1 * wx1_sh[16 + u_ep] + b_sh[16 + u_ep];
      float zg = zr[32 + u_ep] + x0 * wx0_sh[32 + u_ep] + x1 * wx1_sh[32 + u_ep] + b_sh[32 + u_ep];
      float zo = zr[48 + u_ep] + x0 * wx0_sh[48 + u_ep] + x1 * wx1_sh[48 + u_ep] + b_sh[48 + u_ep];
      float ig = fsig(zi), fg = fsig(zf), gg = ftanh(zg), og = fsig(zo);
      float cn = fg * c_reg[q4] + ig * gg;
      float hn = og * ftanh(cn);
      if (!decode) {
        bool m = mask_sh[row] > 0.5f;
        cn = m ? cn : c_reg[q4];
        hn = m ? hn : h_reg[q4];
      }
      c_reg[q4] = cn; h_reg[q4] = hn;

      hsh[row * 16 + u_ep] = (f16)hn;

      if (wr_pred) {
        float p0 = hn * wd_sh[u_ep * 2 + 0];
        float p1 = hn * wd_sh[u_ep * 2 + 1];
#pragma unroll
        for (int m2 = 1; m2 < 16; m2 <<= 1) {
          p0 += __shfl_xor(p0, m2, 64);
          p1 += __shfl_xor(p1, m2, 64);
        }
        if (u_ep == 0) { pps[row * 2] = p0; pps[row * 2 + 1] = p1; }
      }
    }

    // ---------------- per-wave self-bounce: wave w bounces ONLY rows its own lanes
    // ---------------- wrote to hsh/pps (rows 4w..4w+3, 4w+32..35) -> no __syncthreads
    asm volatile("" ::: "memory");                 // keep LDS writes above the reads
    {
      if (lane < 16) {
        int idx = lane >> 1, oct = lane & 1;
        int row = (idx < 4) ? (4 * wid + idx) : (28 + 4 * wid + idx);
        f16x8 hv = *(const f16x8*)(hsh + row * 16 + oct * 8);
        char* dst = (char*)ws + ((s + 1) & 7) * HX_SLOT + mg * 131072 + nblk * 2048
                  + row * 32 + oct * 16;
        ast16(dst, __builtin_bit_cast(i32x4, hv));
      }
      if (wr_pred && lane < 4) {
        int row = (lane < 2) ? (4 * wid + 2 * lane) : (4 * wid + 32 + 2 * (lane - 2));
        f32x4 pv = *(const f32x4*)(pps + row * 2);
        char* dst = (char*)ws + PP_OFF + (size_t)(((s & 7) * 4 + mg) * 64 + nblk) * 512
                  + row * 8;
        ast16(dst, __builtin_bit_cast(i32x4, pv));
      }
      vfence();                                    // drain this wave's stores
    }
    __syncthreads();                               // all waves' stores drained

    // ---------------- per-mg barrier: 64 flags, wide agent-load poll ----------------
    {
      unsigned int* fl = (unsigned int*)((char*)ws + FLG_OFF + mg * 1024);
      if (tid == 0) cst32(fl + nblk, (unsigned int)(s + 1));
      if (tid < 16) {
        const char* fp = (const char*)fl + tid * 16;
        const int tgt = s + 1;
        int guard = 0;
        for (;;) {
          i32x4 f = ald16(fp);
          vfence();
          f = pass(f);
          int mn = imin4(f.x, f.y, f.z, f.w);
          if (__all(mn >= tgt)) break;
          if (++guard > 200000) break;             // bail-out: never hang the bench
          __builtin_amdgcn_s_sleep(1);
        }
      }
      __syncthreads();
    }
  }
  vfence();
}

extern "C" void kernel_launch(void* const* d_in, const int* in_sizes, int n_in,
                              void* d_out, int out_size, void* d_ws, size_t ws_size,
                              hipStream_t stream) {
  const float* inp = (const float*)d_in[0];
  const float* Wx  = (const float*)d_in[1];
  const float* Wh  = (const float*)d_in[2];
  const float* b   = (const float*)d_in[3];
  const float* Wd  = (const float*)d_in[4];
  const float* bd  = (const float*)d_in[5];
  float* out = (float*)d_out;
  unsigned char* ws = (unsigned char*)d_ws;

  init_ws<<<517, 256, 0, stream>>>((unsigned int*)ws);

  hipFuncSetAttribute((const void*)lstm_persist,
                      hipFuncAttributeMaxDynamicSharedMemorySize, LDS_BYTES);
  lstm_persist<<<256, 512, LDS_BYTES, stream>>>(inp, Wx, Wh, b, Wd, bd, out, ws);
}